// Round 8
// baseline (281.894 us; speedup 1.0000x reference)
//
#include <hip/hip_runtime.h>
#include <math.h>

#define N_NODES 50000
#define N_EDGES 800000
#define D_FEAT 128
#define HIDDEN 256
#define NB_SCAN 196           // ceil(50000/256)
#define GEMM_BLOCKS 782       // ceil(50000/64)

#define PREP_CVT_B 512
#define PREP_CNT_B 256
#define PREP_WF_B 64
#define FILL_B 512
#define AGG_B 2048            // 8192 waves

typedef __bf16 bf16x8 __attribute__((ext_vector_type(8)));
typedef float f32x4 __attribute__((ext_vector_type(4)));

__device__ __forceinline__ unsigned f2b(float f) {
    unsigned u = __builtin_bit_cast(unsigned, f);
    return (u + 0x7fff + ((u >> 16) & 1)) >> 16;  // RNE, low 16 bits valid
}

// ---------- fused prep: cvt_x | count | build_wfrag (fat grid-stride blocks) ----------
// xb[node][64 uints]: packed bf16 pairs of x (256 B/row, compact)
__global__ __launch_bounds__(256) void prep(
    const float* __restrict__ x, const int* __restrict__ dst,
    const float* __restrict__ W1l, const float* __restrict__ W1r,
    unsigned* __restrict__ xb, int* __restrict__ cnt,
    unsigned short* __restrict__ Wfrag) {
    int b = blockIdx.x;
    int t = threadIdx.x;
    if (b < PREP_CVT_B) {
        // 800000 uint4 outputs (= 3.2M uints = 6.4M floats)
        for (int g = b * 256 + t; g < 800000; g += PREP_CVT_B * 256) {
            float4 v0 = *(const float4*)(x + (size_t)g * 8);
            float4 v1 = *(const float4*)(x + (size_t)g * 8 + 4);
            uint4 o;
            o.x = f2b(v0.x) | (f2b(v0.y) << 16);
            o.y = f2b(v0.z) | (f2b(v0.w) << 16);
            o.z = f2b(v1.x) | (f2b(v1.y) << 16);
            o.w = f2b(v1.z) | (f2b(v1.w) << 16);
            int d = g >> 4;
            int j = (g & 15) << 2;
            *(uint4*)(xb + (size_t)d * 64 + j) = o;
        }
    } else if (b < PREP_CVT_B + PREP_CNT_B) {
        for (int e = (b - PREP_CVT_B) * 256 + t; e < N_EDGES; e += PREP_CNT_B * 256)
            atomicAdd(&cnt[dst[e]], 1);
    } else {
        for (int tt = (b - PREP_CVT_B - PREP_CNT_B) * 256 + t; tt < 65536;
             tt += PREP_WF_B * 256) {
            int j = tt & 7;
            int lane = (tt >> 3) & 63;
            int ks = (tt >> 9) & 7;
            int nt = tt >> 12;
            int k = ks * 32 + ((lane >> 4) << 3) + j;
            int n = (nt << 4) + (lane & 15);
            float v = (k < 128) ? W1l[k * 256 + n] : W1r[(k - 128) * 256 + n];
            Wfrag[tt] = (unsigned short)f2b(v);
        }
    }
}

// ---------- CSR scan step 1: per-block sums ----------
__global__ void scan1(const int* __restrict__ cnt, int* __restrict__ bsum) {
    __shared__ int tmp[256];
    int t = threadIdx.x;
    int i = blockIdx.x * 256 + t;
    tmp[t] = (i < N_NODES) ? cnt[i] : 0;
    __syncthreads();
    for (int off = 128; off > 0; off >>= 1) {
        if (t < off) tmp[t] += tmp[t + off];
        __syncthreads();
    }
    if (t == 0) bsum[blockIdx.x] = tmp[0];
}

// ---------- CSR scan step 2: row begin offsets ----------
__global__ void scanB(const int* __restrict__ cnt, const int* __restrict__ bsum,
                      int* __restrict__ rowpos) {
    __shared__ int bs[256];
    __shared__ int tmp[256];
    int t = threadIdx.x;
    int b = blockIdx.x;
    bs[t] = (t < NB_SCAN) ? bsum[t] : 0;
    __syncthreads();
    for (int off = 1; off < 256; off <<= 1) {
        int y = (t >= off) ? bs[t - off] : 0;
        __syncthreads();
        bs[t] += y;
        __syncthreads();
    }
    int boff = (b == 0) ? 0 : bs[b - 1];
    int i = b * 256 + t;
    int v = (i < N_NODES) ? cnt[i] : 0;
    tmp[t] = v;
    __syncthreads();
    for (int off = 1; off < 256; off <<= 1) {
        int y = (t >= off) ? tmp[t - off] : 0;
        __syncthreads();
        tmp[t] += y;
        __syncthreads();
    }
    if (i < N_NODES) rowpos[i] = tmp[t] - v + boff;  // exclusive begin
}

// after fill, rowpos[d] == end offset; beg = end - cnt[d]
__global__ __launch_bounds__(256) void fill_kernel(
    const int* __restrict__ src, const int* __restrict__ dst,
    int* __restrict__ rowpos, unsigned short* __restrict__ esrc) {
    for (int e = blockIdx.x * 256 + threadIdx.x; e < N_EDGES; e += FILL_B * 256) {
        int pos = atomicAdd(&rowpos[dst[e]], 1);
        esrc[pos] = (unsigned short)src[e];
    }
}

// ---------- fused: gather-mean -> LDS, MFMA GEMM, ps epilogue ----------
// 64 rows/block, 512 threads (8 waves). Wave w gathers rows w*8..w*8+7,
// then owns output cols w*32..w*32+31.
// h = relu([mean|x]@Wcat + b1); p = h@W2l; s = h@W2r + b2
__global__ __launch_bounds__(512) void gemm1ps(
    const unsigned* __restrict__ xb, const unsigned short* __restrict__ esrc,
    const int* __restrict__ rowend, const int* __restrict__ cnt,
    const unsigned short* __restrict__ Wfrag, const float* __restrict__ b1,
    const float* __restrict__ W2l, const float* __restrict__ W2r,
    const float* __restrict__ b2,
    float* __restrict__ h, float* __restrict__ p, float* __restrict__ s) {
    __shared__ unsigned A[64 * 128];   // 32 KB, 16B-chunk XOR swizzled
    __shared__ float ppart[64][4];     // p0,p1,s0,s1 partials per row

    int r0 = blockIdx.x * 64;
    int tid = threadIdx.x;
    int w = tid >> 6;          // 0..7
    int lane = tid & 63;
    int quad = lane >> 4;
    int l15 = lane & 15;

    if (tid < 256) ((float*)ppart)[tid] = 0.0f;

    // ---- gather phase: wave w handles rows w*8 .. w*8+7 ----
    // lane owns feature pair `lane`; mean -> LDS word `lane`, x -> word 64+lane
    int cm = lane >> 2;            // chunk of mean word
    int cx = 16 + (lane >> 2);     // chunk of x word
    int wo = lane & 3;             // word within chunk
    for (int rr = 0; rr < 8; rr++) {
        int lr = (w << 3) + rr;
        int d = r0 + lr;
        unsigned mword = 0, xword = 0;
        if (d < N_NODES) {
            int end = rowend[d];
            int c = cnt[d];
            float a0 = 0.0f, a1 = 0.0f;
            for (int base = end - c; base < end; base += 64) {
                int m = end - base; if (m > 64) m = 64;
                int idx = base + lane;
                int e = (int)esrc[idx < end ? idx : end - 1];  // coalesced, clamped
                for (int j0 = 0; j0 < m; j0 += 8) {
#pragma unroll
                    for (int j = 0; j < 8; j++) {
                        int ss = __shfl(e, j0 + j);                 // broadcast
                        unsigned u = xb[(size_t)ss * 64 + lane];    // 2 bf16
                        float sc = (j0 + j < m) ? 1.0f : 0.0f;      // uniform mask
                        a0 += sc * __builtin_bit_cast(float, u << 16);
                        a1 += sc * __builtin_bit_cast(float, u & 0xffff0000u);
                    }
                }
            }
            float inv = 1.0f / fmaxf((float)c, 1.0f);
            mword = f2b(a0 * inv) | (f2b(a1 * inv) << 16);
            xword = xb[(size_t)d * 64 + lane];
        }
        A[lr * 128 + ((cm ^ (lr & 7)) << 2) + wo] = mword;
        A[lr * 128 + ((cx ^ (lr & 7)) << 2) + wo] = xword;
    }
    __syncthreads();

    // ---- MFMA phase: wave w computes cols w*32..w*32+31 ----
    f32x4 acc[8];  // [mt][nt], nt in {0,1}
#pragma unroll
    for (int i = 0; i < 8; i++) acc[i] = (f32x4){0.0f, 0.0f, 0.0f, 0.0f};

    uint4 braw[2];
#pragma unroll
    for (int nt = 0; nt < 2; nt++)
        braw[nt] = *(const uint4*)(Wfrag + ((((w * 2 + nt) << 3) + 0) * 64 + lane) * 8);

    for (int ks = 0; ks < 8; ks++) {
        bf16x8 bfr[2];
        bfr[0] = __builtin_bit_cast(bf16x8, braw[0]);
        bfr[1] = __builtin_bit_cast(bf16x8, braw[1]);
        if (ks < 7) {
#pragma unroll
            for (int nt = 0; nt < 2; nt++)
                braw[nt] = *(const uint4*)(
                    Wfrag + ((((w * 2 + nt) << 3) + ks + 1) * 64 + lane) * 8);
        }
#pragma unroll
        for (int mt = 0; mt < 4; mt++) {
            int row = (mt << 4) + l15;
            int c = (ks << 2) + quad;
            uint4 araw = *(const uint4*)(A + row * 128 + ((c ^ (row & 7)) << 2));
            bf16x8 afr = __builtin_bit_cast(bf16x8, araw);
#pragma unroll
            for (int nt = 0; nt < 2; nt++) {
                acc[(mt << 1) + nt] = __builtin_amdgcn_mfma_f32_16x16x32_bf16(
                    afr, bfr[nt], acc[(mt << 1) + nt], 0, 0, 0);
            }
        }
    }

    // ---- epilogue: relu + h store + ps partials. D layout: col=l15, row=quad*4+reg ----
    float w2[2][4];
#pragma unroll
    for (int nt = 0; nt < 2; nt++) {
        int col = (w << 5) + (nt << 4) + l15;
        float2 l2 = *(const float2*)(W2l + col * 2);
        float2 r2 = *(const float2*)(W2r + col * 2);
        w2[nt][0] = l2.x; w2[nt][1] = l2.y; w2[nt][2] = r2.x; w2[nt][3] = r2.y;
    }

#pragma unroll
    for (int mt = 0; mt < 4; mt++) {
        float red[4][4];
#pragma unroll
        for (int v = 0; v < 4; v++)
#pragma unroll
            for (int r = 0; r < 4; r++) red[v][r] = 0.0f;

#pragma unroll
        for (int nt = 0; nt < 2; nt++) {
            int col = (w << 5) + (nt << 4) + l15;
            float b = b1[col];
            f32x4 v = acc[(mt << 1) + nt];
#pragma unroll
            for (int r = 0; r < 4; r++) {
                float hv = v[r] + b;
                hv = hv > 0.0f ? hv : 0.0f;
                int row = r0 + (mt << 4) + (quad << 2) + r;
                if (row < N_NODES) h[(size_t)row * 256 + col] = hv;
                red[0][r] += hv * w2[nt][0];
                red[1][r] += hv * w2[nt][1];
                red[2][r] += hv * w2[nt][2];
                red[3][r] += hv * w2[nt][3];
            }
        }
#pragma unroll
        for (int v = 0; v < 4; v++)
#pragma unroll
            for (int r = 0; r < 4; r++) {
                red[v][r] += __shfl_xor(red[v][r], 1);
                red[v][r] += __shfl_xor(red[v][r], 2);
                red[v][r] += __shfl_xor(red[v][r], 4);
                red[v][r] += __shfl_xor(red[v][r], 8);
            }
        if (l15 == 0) {
            int lrow = (mt << 4) + (quad << 2);
#pragma unroll
            for (int r = 0; r < 4; r++)
#pragma unroll
                for (int v = 0; v < 4; v++)
                    atomicAdd(&ppart[lrow + r][v], red[v][r]);
        }
    }
    __syncthreads();

    if (tid < 64) {
        int row = r0 + tid;
        if (row < N_NODES) {
            float2 pv = {ppart[tid][0], ppart[tid][1]};
            float2 sv = {ppart[tid][2] + b2[0], ppart[tid][3] + b2[1]};
            *(float2*)(p + (size_t)row * 2) = pv;
            *(float2*)(s + (size_t)row * 2) = sv;
        }
    }
}

// ---------- layer-2: wave-per-node grid-stride, gather-mean of p + sigmoid ----------
__global__ __launch_bounds__(256) void agg2(
    const float* __restrict__ p, const float* __restrict__ s,
    const unsigned short* __restrict__ esrc,
    const int* __restrict__ rowend, const int* __restrict__ cnt,
    float* __restrict__ out) {
    int wid = (blockIdx.x * 256 + threadIdx.x) >> 6;
    int lane = threadIdx.x & 63;
    for (int d = wid; d < N_NODES; d += AGG_B * 4) {
        int end = rowend[d];
        int c = cnt[d];
        float a0 = 0.0f, a1 = 0.0f;
        for (int base = end - c; base < end; base += 64) {
            int idx = base + lane;
            if (idx < end) {
                int ss = (int)esrc[idx];
                float2 v = *(const float2*)(p + (size_t)ss * 2);
                a0 += v.x; a1 += v.y;
            }
        }
#pragma unroll
        for (int off = 32; off > 0; off >>= 1) {
            a0 += __shfl_down(a0, off);
            a1 += __shfl_down(a1, off);
        }
        if (lane == 0) {
            float inv = 1.0f / fmaxf((float)c, 1.0f);
            float z0 = a0 * inv + s[(size_t)d * 2 + 0];
            float z1 = a1 * inv + s[(size_t)d * 2 + 1];
            float2 o = {1.0f / (1.0f + expf(-z0)), 1.0f / (1.0f + expf(-z1))};
            *(float2*)(out + (size_t)d * 2) = o;
        }
    }
}

extern "C" void kernel_launch(void* const* d_in, const int* in_sizes, int n_in,
                              void* d_out, int out_size, void* d_ws, size_t ws_size,
                              hipStream_t stream) {
    const float* x   = (const float*)d_in[0];
    const int*   ei  = (const int*)d_in[1];
    const float* W1l = (const float*)d_in[2];
    const float* W1r = (const float*)d_in[3];
    const float* b1  = (const float*)d_in[4];
    const float* W2l = (const float*)d_in[5];
    const float* W2r = (const float*)d_in[6];
    const float* b2  = (const float*)d_in[7];

    const int* src = ei;
    const int* dst = ei + N_EDGES;

    float* out = (float*)d_out;               // [50000, 2]
    float* emb = out + (size_t)N_NODES * 2;   // [50000, 256] == h

    // ---- workspace layout (~16 MB) ----
    int* cnt    = (int*)d_ws;                             // 50000
    int* rowpos = cnt + N_NODES;                          // 50000
    int* bsum   = rowpos + N_NODES;                       // 256
    unsigned short* esrc = (unsigned short*)(bsum + 256); // 800064 (16B-mult pad)
    unsigned* xb = (unsigned*)(esrc + 800064);            // 50000 x 64 uints (12.8 MB)
    unsigned short* Wfrag = (unsigned short*)(xb + (size_t)N_NODES * 64);  // 65536
    float* p = (float*)(Wfrag + 65536);                   // 100000
    float* s = p + (size_t)N_NODES * 2;                   // 100000

    hipMemsetAsync(cnt, 0, N_NODES * sizeof(int), stream);

    prep<<<PREP_CVT_B + PREP_CNT_B + PREP_WF_B, 256, 0, stream>>>(
        x, dst, W1l, W1r, xb, cnt, Wfrag);

    scan1<<<NB_SCAN, 256, 0, stream>>>(cnt, bsum);
    scanB<<<NB_SCAN, 256, 0, stream>>>(cnt, bsum, rowpos);
    fill_kernel<<<FILL_B, 256, 0, stream>>>(src, dst, rowpos, esrc);

    gemm1ps<<<GEMM_BLOCKS, 512, 0, stream>>>(xb, esrc, rowpos, cnt, Wfrag,
                                             b1, W2l, W2r, b2, emb, p, s);

    agg2<<<AGG_B, 256, 0, stream>>>(p, s, esrc, rowpos, cnt, out);
}

// Round 9
// 259.046 us; speedup vs baseline: 1.0882x; 1.0882x over previous
//
#include <hip/hip_runtime.h>
#include <math.h>

#define N_NODES 50000
#define N_EDGES 800000
#define D_FEAT 128
#define HIDDEN 256
#define NB_SCAN 196           // ceil(50000/256)
#define GEMM_BLOCKS 1563      // ceil(50000/32)

#define PREP_CVT_B 512
#define PREP_CNT_B 256
#define PREP_WF_B 64
#define FILL_B 512
#define AGG_B 2048            // 8192 waves

typedef __bf16 bf16x8 __attribute__((ext_vector_type(8)));
typedef float f32x4 __attribute__((ext_vector_type(4)));

__device__ __forceinline__ unsigned f2b(float f) {
    unsigned u = __builtin_bit_cast(unsigned, f);
    return (u + 0x7fff + ((u >> 16) & 1)) >> 16;  // RNE, low 16 bits valid
}

// ---------- fused prep: cvt_x | count | build_wfrag (fat grid-stride blocks) ----------
// xb[node][64 uints]: packed bf16 pairs of x (256 B/row, compact)
__global__ __launch_bounds__(256) void prep(
    const float* __restrict__ x, const int* __restrict__ dst,
    const float* __restrict__ W1l, const float* __restrict__ W1r,
    unsigned* __restrict__ xb, int* __restrict__ cnt,
    unsigned short* __restrict__ Wfrag) {
    int b = blockIdx.x;
    int t = threadIdx.x;
    if (b < PREP_CVT_B) {
        for (int g = b * 256 + t; g < 800000; g += PREP_CVT_B * 256) {
            float4 v0 = *(const float4*)(x + (size_t)g * 8);
            float4 v1 = *(const float4*)(x + (size_t)g * 8 + 4);
            uint4 o;
            o.x = f2b(v0.x) | (f2b(v0.y) << 16);
            o.y = f2b(v0.z) | (f2b(v0.w) << 16);
            o.z = f2b(v1.x) | (f2b(v1.y) << 16);
            o.w = f2b(v1.z) | (f2b(v1.w) << 16);
            int d = g >> 4;
            int j = (g & 15) << 2;
            *(uint4*)(xb + (size_t)d * 64 + j) = o;
        }
    } else if (b < PREP_CVT_B + PREP_CNT_B) {
        for (int e = (b - PREP_CVT_B) * 256 + t; e < N_EDGES; e += PREP_CNT_B * 256)
            atomicAdd(&cnt[dst[e]], 1);
    } else {
        for (int tt = (b - PREP_CVT_B - PREP_CNT_B) * 256 + t; tt < 65536;
             tt += PREP_WF_B * 256) {
            int j = tt & 7;
            int lane = (tt >> 3) & 63;
            int ks = (tt >> 9) & 7;
            int nt = tt >> 12;
            int k = ks * 32 + ((lane >> 4) << 3) + j;
            int n = (nt << 4) + (lane & 15);
            float v = (k < 128) ? W1l[k * 256 + n] : W1r[(k - 128) * 256 + n];
            Wfrag[tt] = (unsigned short)f2b(v);
        }
    }
}

// ---------- CSR scan step 1: per-block sums ----------
__global__ void scan1(const int* __restrict__ cnt, int* __restrict__ bsum) {
    __shared__ int tmp[256];
    int t = threadIdx.x;
    int i = blockIdx.x * 256 + t;
    tmp[t] = (i < N_NODES) ? cnt[i] : 0;
    __syncthreads();
    for (int off = 128; off > 0; off >>= 1) {
        if (t < off) tmp[t] += tmp[t + off];
        __syncthreads();
    }
    if (t == 0) bsum[blockIdx.x] = tmp[0];
}

// ---------- CSR scan step 2: row begin offsets ----------
__global__ void scanB(const int* __restrict__ cnt, const int* __restrict__ bsum,
                      int* __restrict__ rowpos) {
    __shared__ int bs[256];
    __shared__ int tmp[256];
    int t = threadIdx.x;
    int b = blockIdx.x;
    bs[t] = (t < NB_SCAN) ? bsum[t] : 0;
    __syncthreads();
    for (int off = 1; off < 256; off <<= 1) {
        int y = (t >= off) ? bs[t - off] : 0;
        __syncthreads();
        bs[t] += y;
        __syncthreads();
    }
    int boff = (b == 0) ? 0 : bs[b - 1];
    int i = b * 256 + t;
    int v = (i < N_NODES) ? cnt[i] : 0;
    tmp[t] = v;
    __syncthreads();
    for (int off = 1; off < 256; off <<= 1) {
        int y = (t >= off) ? tmp[t - off] : 0;
        __syncthreads();
        tmp[t] += y;
        __syncthreads();
    }
    if (i < N_NODES) rowpos[i] = tmp[t] - v + boff;  // exclusive begin
}

// after fill, rowpos[d] == end offset; beg = end - cnt[d]
__global__ __launch_bounds__(256) void fill_kernel(
    const int* __restrict__ src, const int* __restrict__ dst,
    int* __restrict__ rowpos, unsigned short* __restrict__ esrc) {
    for (int e = blockIdx.x * 256 + threadIdx.x; e < N_EDGES; e += FILL_B * 256) {
        int pos = atomicAdd(&rowpos[dst[e]], 1);
        esrc[pos] = (unsigned short)src[e];
    }
}

// ---------- agg1: wave-per-node grid-stride gather-mean of xb -> compact mb ----------
// Pure gather kernel: no large store stream competing for L2/L3 residency of xb.
__global__ __launch_bounds__(256) void agg1(
    const unsigned* __restrict__ xb, unsigned* __restrict__ mb,
    const unsigned short* __restrict__ esrc,
    const int* __restrict__ rowend, const int* __restrict__ cnt) {
    int wid = (blockIdx.x * 256 + threadIdx.x) >> 6;   // 8192 waves
    int lane = threadIdx.x & 63;
    for (int d = wid; d < N_NODES; d += AGG_B * 4) {
        int end = rowend[d];
        int c = cnt[d];
        float a0 = 0.0f, a1 = 0.0f;
        for (int base = end - c; base < end; base += 64) {
            int m = end - base; if (m > 64) m = 64;
            int idx = base + lane;
            int e = (int)esrc[idx < end ? idx : end - 1];  // coalesced, clamped
            for (int j0 = 0; j0 < m; j0 += 8) {
#pragma unroll
                for (int j = 0; j < 8; j++) {
                    int ss = __shfl(e, j0 + j);                 // broadcast
                    unsigned u = xb[(size_t)ss * 64 + lane];    // 2 bf16
                    float sc = (j0 + j < m) ? 1.0f : 0.0f;      // uniform mask
                    a0 += sc * __builtin_bit_cast(float, u << 16);
                    a1 += sc * __builtin_bit_cast(float, u & 0xffff0000u);
                }
            }
        }
        float inv = 1.0f / fmaxf((float)c, 1.0f);
        mb[(size_t)d * 64 + lane] = f2b(a0 * inv) | (f2b(a1 * inv) << 16);
    }
}

// ---------- gemm1 + fused ps: h = relu([mean|x]@Wcat + b1); p = h@W2l; s = h@W2r+b2 ----------
// 32 rows/block, 256 threads (4 waves); wave w owns cols w*64..w*64+63.
// h written nontemporal (pure streaming output, never re-read).
__global__ __launch_bounds__(256) void gemm1ps(
    const unsigned* __restrict__ mb, const unsigned* __restrict__ xb,
    const unsigned short* __restrict__ Wfrag, const float* __restrict__ b1,
    const float* __restrict__ W2l, const float* __restrict__ W2r,
    const float* __restrict__ b2,
    float* __restrict__ h, float* __restrict__ p, float* __restrict__ s) {
    __shared__ unsigned A[32 * 128];   // 16 KB, 16B-chunk XOR swizzled (k0-127: mean|x)
    __shared__ float ppart[32][4];     // p0,p1,s0,s1 partials per row

    int r0 = blockIdx.x * 32;
    int tid = threadIdx.x;
    int w = tid >> 6;          // 0..3
    int lane = tid & 63;
    int quad = lane >> 4;
    int l15 = lane & 15;

    if (tid < 128) ((float*)ppart)[tid] = 0.0f;

    // ---- stage A tile: thread t -> row t>>3, chunks (t&7)+8j; chunk<16=mean, else x ----
    int sr = tid >> 3;
    int c0 = tid & 7;
#pragma unroll
    for (int j = 0; j < 4; j++) {
        int c = c0 + (j << 3);             // 0..31
        uint4 v;
        if (c < 16) v = *(const uint4*)(mb + (size_t)(r0 + sr) * 64 + (c << 2));
        else        v = *(const uint4*)(xb + (size_t)(r0 + sr) * 64 + ((c - 16) << 2));
        int cp = c ^ (sr & 7);
        *(uint4*)(A + sr * 128 + (cp << 2)) = v;
    }
    __syncthreads();

    // ---- MFMA: 8 K-chunks of 32, 2 row-tiles x 4 col-tiles ----
    f32x4 acc[8];
#pragma unroll
    for (int i = 0; i < 8; i++) acc[i] = (f32x4){0.0f, 0.0f, 0.0f, 0.0f};

    for (int ks = 0; ks < 8; ks++) {
        bf16x8 bfr[4];
#pragma unroll
        for (int nt = 0; nt < 4; nt++) {
            int ntg = (w << 2) + nt;
            uint4 raw = *(const uint4*)(Wfrag + ((((ntg << 3) + ks) << 6) + lane) * 8);
            bfr[nt] = __builtin_bit_cast(bf16x8, raw);
        }
#pragma unroll
        for (int mt = 0; mt < 2; mt++) {
            int row = (mt << 4) + l15;
            int c = (ks << 2) + quad;
            uint4 araw = *(const uint4*)(A + row * 128 + ((c ^ (row & 7)) << 2));
            bf16x8 afr = __builtin_bit_cast(bf16x8, araw);
#pragma unroll
            for (int nt = 0; nt < 4; nt++) {
                acc[(mt << 2) + nt] = __builtin_amdgcn_mfma_f32_16x16x32_bf16(
                    afr, bfr[nt], acc[(mt << 2) + nt], 0, 0, 0);
            }
        }
    }

    // ---- epilogue: relu + nontemporal h store + ps partials ----
    float w2[4][4];
#pragma unroll
    for (int nt = 0; nt < 4; nt++) {
        int col = (w << 6) + (nt << 4) + l15;
        float2 l2 = *(const float2*)(W2l + col * 2);
        float2 r2 = *(const float2*)(W2r + col * 2);
        w2[nt][0] = l2.x; w2[nt][1] = l2.y; w2[nt][2] = r2.x; w2[nt][3] = r2.y;
    }

#pragma unroll
    for (int mt = 0; mt < 2; mt++) {
        float red[4][4];
#pragma unroll
        for (int v = 0; v < 4; v++)
#pragma unroll
            for (int r = 0; r < 4; r++) red[v][r] = 0.0f;

#pragma unroll
        for (int nt = 0; nt < 4; nt++) {
            int col = (w << 6) + (nt << 4) + l15;
            float b = b1[col];
            f32x4 v = acc[(mt << 2) + nt];
#pragma unroll
            for (int r = 0; r < 4; r++) {
                float hv = v[r] + b;
                hv = hv > 0.0f ? hv : 0.0f;
                int row = r0 + (mt << 4) + (quad << 2) + r;
                if (row < N_NODES)
                    __builtin_nontemporal_store(hv, &h[(size_t)row * 256 + col]);
                red[0][r] += hv * w2[nt][0];
                red[1][r] += hv * w2[nt][1];
                red[2][r] += hv * w2[nt][2];
                red[3][r] += hv * w2[nt][3];
            }
        }
#pragma unroll
        for (int v = 0; v < 4; v++)
#pragma unroll
            for (int r = 0; r < 4; r++) {
                red[v][r] += __shfl_xor(red[v][r], 1);
                red[v][r] += __shfl_xor(red[v][r], 2);
                red[v][r] += __shfl_xor(red[v][r], 4);
                red[v][r] += __shfl_xor(red[v][r], 8);
            }
        if (l15 == 0) {
            int lrow = (mt << 4) + (quad << 2);
#pragma unroll
            for (int r = 0; r < 4; r++)
#pragma unroll
                for (int v = 0; v < 4; v++)
                    atomicAdd(&ppart[lrow + r][v], red[v][r]);
        }
    }
    __syncthreads();

    if (tid < 32) {
        int row = r0 + tid;
        if (row < N_NODES) {
            float2 pv = {ppart[tid][0], ppart[tid][1]};
            float2 sv = {ppart[tid][2] + b2[0], ppart[tid][3] + b2[1]};
            *(float2*)(p + (size_t)row * 2) = pv;
            *(float2*)(s + (size_t)row * 2) = sv;
        }
    }
}

// ---------- layer-2: wave-per-node grid-stride, gather-mean of p + sigmoid ----------
__global__ __launch_bounds__(256) void agg2(
    const float* __restrict__ p, const float* __restrict__ s,
    const unsigned short* __restrict__ esrc,
    const int* __restrict__ rowend, const int* __restrict__ cnt,
    float* __restrict__ out) {
    int wid = (blockIdx.x * 256 + threadIdx.x) >> 6;
    int lane = threadIdx.x & 63;
    for (int d = wid; d < N_NODES; d += AGG_B * 4) {
        int end = rowend[d];
        int c = cnt[d];
        float a0 = 0.0f, a1 = 0.0f;
        for (int base = end - c; base < end; base += 64) {
            int idx = base + lane;
            if (idx < end) {
                int ss = (int)esrc[idx];
                float2 v = *(const float2*)(p + (size_t)ss * 2);
                a0 += v.x; a1 += v.y;
            }
        }
#pragma unroll
        for (int off = 32; off > 0; off >>= 1) {
            a0 += __shfl_down(a0, off);
            a1 += __shfl_down(a1, off);
        }
        if (lane == 0) {
            float inv = 1.0f / fmaxf((float)c, 1.0f);
            float z0 = a0 * inv + s[(size_t)d * 2 + 0];
            float z1 = a1 * inv + s[(size_t)d * 2 + 1];
            float2 o = {1.0f / (1.0f + expf(-z0)), 1.0f / (1.0f + expf(-z1))};
            *(float2*)(out + (size_t)d * 2) = o;
        }
    }
}

extern "C" void kernel_launch(void* const* d_in, const int* in_sizes, int n_in,
                              void* d_out, int out_size, void* d_ws, size_t ws_size,
                              hipStream_t stream) {
    const float* x   = (const float*)d_in[0];
    const int*   ei  = (const int*)d_in[1];
    const float* W1l = (const float*)d_in[2];
    const float* W1r = (const float*)d_in[3];
    const float* b1  = (const float*)d_in[4];
    const float* W2l = (const float*)d_in[5];
    const float* W2r = (const float*)d_in[6];
    const float* b2  = (const float*)d_in[7];

    const int* src = ei;
    const int* dst = ei + N_EDGES;

    float* out = (float*)d_out;               // [50000, 2]
    float* emb = out + (size_t)N_NODES * 2;   // [50000, 256] == h

    // ---- workspace layout (~29 MB); xb/mb padded to 50048 rows so tile 1562's
    //      staging reads (rows up to 50015) stay in-bounds ----
    int* cnt    = (int*)d_ws;                             // 50000
    int* rowpos = cnt + N_NODES;                          // 50000
    int* bsum   = rowpos + N_NODES;                       // 256
    unsigned short* esrc = (unsigned short*)(bsum + 256); // 800064 (16B-mult pad)
    unsigned* xb = (unsigned*)(esrc + 800064);            // 50048 x 64 uints
    unsigned* mb = xb + (size_t)50048 * 64;               // 50048 x 64 uints
    unsigned short* Wfrag = (unsigned short*)(mb + (size_t)50048 * 64);  // 65536
    float* p = (float*)(Wfrag + 65536);                   // 100000
    float* s = p + (size_t)N_NODES * 2;                   // 100000

    hipMemsetAsync(cnt, 0, N_NODES * sizeof(int), stream);

    prep<<<PREP_CVT_B + PREP_CNT_B + PREP_WF_B, 256, 0, stream>>>(
        x, dst, W1l, W1r, xb, cnt, Wfrag);

    scan1<<<NB_SCAN, 256, 0, stream>>>(cnt, bsum);
    scanB<<<NB_SCAN, 256, 0, stream>>>(cnt, bsum, rowpos);
    fill_kernel<<<FILL_B, 256, 0, stream>>>(src, dst, rowpos, esrc);

    agg1<<<AGG_B, 256, 0, stream>>>(xb, mb, esrc, rowpos, cnt);

    gemm1ps<<<GEMM_BLOCKS, 256, 0, stream>>>(mb, xb, Wfrag, b1, W2l, W2r, b2,
                                             emb, p, s);

    agg2<<<AGG_B, 256, 0, stream>>>(p, s, esrc, rowpos, cnt, out);
}

// Round 10
// 239.226 us; speedup vs baseline: 1.1784x; 1.0829x over previous
//
#include <hip/hip_runtime.h>
#include <math.h>

#define N_NODES 50000
#define N_EDGES 800000
#define D_FEAT 128
#define HIDDEN 256
#define NB_SCAN 196           // ceil(50000/256)
#define GEMM_BLOCKS 1563      // ceil(50000/32)

#define PREP_CVT_B 512
#define PREP_WF_B 64
#define AGG_B 2048            // 8192 waves

#define NSLICE 64             // edge slices for CSR build
#define SLICE_E 12500         // 800000 / 64
#define NPART 8               // node partitions for scatter
#define PART_N 6250           // 50000 / 8

typedef __bf16 bf16x8 __attribute__((ext_vector_type(8)));
typedef float f32x4 __attribute__((ext_vector_type(4)));

__device__ __forceinline__ unsigned f2b(float f) {
    unsigned u = __builtin_bit_cast(unsigned, f);
    return (u + 0x7fff + ((u >> 16) & 1)) >> 16;  // RNE, low 16 bits valid
}

// ---------- fused prep: cvt_x | build_wfrag ----------
// xb[node][64 uints]: packed bf16 pairs of x (256 B/row, compact)
__global__ __launch_bounds__(256) void prep(
    const float* __restrict__ x,
    const float* __restrict__ W1l, const float* __restrict__ W1r,
    unsigned* __restrict__ xb, unsigned short* __restrict__ Wfrag) {
    int b = blockIdx.x;
    int t = threadIdx.x;
    if (b < PREP_CVT_B) {
        for (int g = b * 256 + t; g < 800000; g += PREP_CVT_B * 256) {
            float4 v0 = *(const float4*)(x + (size_t)g * 8);
            float4 v1 = *(const float4*)(x + (size_t)g * 8 + 4);
            uint4 o;
            o.x = f2b(v0.x) | (f2b(v0.y) << 16);
            o.y = f2b(v0.z) | (f2b(v0.w) << 16);
            o.z = f2b(v1.x) | (f2b(v1.y) << 16);
            o.w = f2b(v1.z) | (f2b(v1.w) << 16);
            int d = g >> 4;
            int j = (g & 15) << 2;
            *(uint4*)(xb + (size_t)d * 64 + j) = o;
        }
    } else {
        for (int tt = (b - PREP_CVT_B) * 256 + t; tt < 65536; tt += PREP_WF_B * 256) {
            int j = tt & 7;
            int lane = (tt >> 3) & 63;
            int ks = (tt >> 9) & 7;
            int nt = tt >> 12;
            int k = ks * 32 + ((lane >> 4) << 3) + j;
            int n = (nt << 4) + (lane & 15);
            float v = (k < 128) ? W1l[k * 256 + n] : W1r[(k - 128) * 256 + n];
            Wfrag[tt] = (unsigned short)f2b(v);
        }
    }
}

// ---------- CSR step A: per-slice full histogram (LDS, u16-packed) ----------
// arr[i][d] = #edges in slice i with dst==d   (slice = 12500 edges)
__global__ __launch_bounds__(256) void hist_kernel(const int* __restrict__ dst,
                                                   unsigned* __restrict__ arr) {
    __shared__ unsigned hist[25000];   // 100 KB: 50000 u16 counters, 2 per word
    int i = blockIdx.x;
    int t = threadIdx.x;
    for (int k = t; k < 25000; k += 256) hist[k] = 0;
    __syncthreads();
    int e0 = i * SLICE_E;
    for (int k = t; k < SLICE_E; k += 256) {
        int d = dst[e0 + k];
        atomicAdd(&hist[d >> 1], (d & 1) ? 65536u : 1u);   // LDS atomic
    }
    __syncthreads();
    for (int d = t; d < N_NODES; d += 256)
        arr[(size_t)i * N_NODES + d] = (hist[d >> 1] >> ((d & 1) << 4)) & 0xffffu;
}

// ---------- CSR step B: cnt[d] = sum over slices; per-block sums for scan ----------
__global__ void scan1(const unsigned* __restrict__ arr, int* __restrict__ cnt,
                      int* __restrict__ bsum) {
    __shared__ int tmp[256];
    int t = threadIdx.x;
    int i = blockIdx.x * 256 + t;
    int c = 0;
    if (i < N_NODES) {
        for (int k = 0; k < NSLICE; k++) c += (int)arr[(size_t)k * N_NODES + i];
        cnt[i] = c;
    }
    tmp[t] = c;
    __syncthreads();
    for (int off = 128; off > 0; off >>= 1) {
        if (t < off) tmp[t] += tmp[t + off];
        __syncthreads();
    }
    if (t == 0) bsum[blockIdx.x] = tmp[0];
}

// ---------- CSR step C: exclusive scan -> rowbeg ----------
__global__ void scanB(const int* __restrict__ cnt, const int* __restrict__ bsum,
                      int* __restrict__ rowbeg) {
    __shared__ int bs[256];
    __shared__ int tmp[256];
    int t = threadIdx.x;
    int b = blockIdx.x;
    bs[t] = (t < NB_SCAN) ? bsum[t] : 0;
    __syncthreads();
    for (int off = 1; off < 256; off <<= 1) {
        int y = (t >= off) ? bs[t - off] : 0;
        __syncthreads();
        bs[t] += y;
        __syncthreads();
    }
    int boff = (b == 0) ? 0 : bs[b - 1];
    int i = b * 256 + t;
    int v = (i < N_NODES) ? cnt[i] : 0;
    tmp[t] = v;
    __syncthreads();
    for (int off = 1; off < 256; off <<= 1) {
        int y = (t >= off) ? tmp[t - off] : 0;
        __syncthreads();
        tmp[t] += y;
        __syncthreads();
    }
    if (i < N_NODES) rowbeg[i] = tmp[t] - v + boff;
}

// ---------- CSR step D: in-place prefix over slices -> per-(slice,node) base ----------
__global__ __launch_bounds__(256) void offs_kernel(const int* __restrict__ rowbeg,
                                                   unsigned* __restrict__ arr) {
    int d = blockIdx.x * 256 + threadIdx.x;
    if (d >= N_NODES) return;
    unsigned running = (unsigned)rowbeg[d];
#pragma unroll 4
    for (int k = 0; k < NSLICE; k++) {
        unsigned old = arr[(size_t)k * N_NODES + d];
        arr[(size_t)k * N_NODES + d] = running;
        running += old;
    }
}

// ---------- CSR step E: deterministic scatter, LDS cursors only ----------
// block (g,i): partition g of nodes, slice i of edges
__global__ __launch_bounds__(256) void scatter_kernel(
    const int* __restrict__ src, const int* __restrict__ dst,
    const unsigned* __restrict__ arr, unsigned short* __restrict__ esrc) {
    __shared__ unsigned off[PART_N];   // 25 KB
    int g = blockIdx.x & 7;            // ~XCD id (locality heuristic only)
    int i = blockIdx.x >> 3;
    int t = threadIdx.x;
    int lo = g * PART_N;
    for (int k = t; k < PART_N; k += 256)
        off[k] = arr[(size_t)i * N_NODES + lo + k];
    __syncthreads();
    int e0 = i * SLICE_E;
    for (int k = t; k < SLICE_E; k += 256) {
        int e = e0 + k;
        int d = dst[e];
        unsigned dl = (unsigned)(d - lo);
        if (dl < (unsigned)PART_N) {
            unsigned pos = atomicAdd(&off[dl], 1u);   // LDS atomic
            esrc[pos] = (unsigned short)src[e];
        }
    }
}

// ---------- agg1: wave-per-node grid-stride gather-mean of xb -> compact mb ----------
__global__ __launch_bounds__(256) void agg1(
    const unsigned* __restrict__ xb, unsigned* __restrict__ mb,
    const unsigned short* __restrict__ esrc,
    const int* __restrict__ rowbeg, const int* __restrict__ cnt) {
    int wid = (blockIdx.x * 256 + threadIdx.x) >> 6;   // 8192 waves
    int lane = threadIdx.x & 63;
    for (int d = wid; d < N_NODES; d += AGG_B * 4) {
        int beg = rowbeg[d];
        int c = cnt[d];
        int end = beg + c;
        float a0 = 0.0f, a1 = 0.0f;
        for (int base = beg; base < end; base += 64) {
            int m = end - base; if (m > 64) m = 64;
            int idx = base + lane;
            int e = (int)esrc[idx < end ? idx : end - 1];  // coalesced, clamped
            for (int j0 = 0; j0 < m; j0 += 8) {
#pragma unroll
                for (int j = 0; j < 8; j++) {
                    int ss = __shfl(e, j0 + j);                 // broadcast
                    unsigned u = xb[(size_t)ss * 64 + lane];    // 2 bf16
                    float sc = (j0 + j < m) ? 1.0f : 0.0f;      // uniform mask
                    a0 += sc * __builtin_bit_cast(float, u << 16);
                    a1 += sc * __builtin_bit_cast(float, u & 0xffff0000u);
                }
            }
        }
        float inv = 1.0f / fmaxf((float)c, 1.0f);
        mb[(size_t)d * 64 + lane] = f2b(a0 * inv) | (f2b(a1 * inv) << 16);
    }
}

// ---------- gemm1 + fused ps: h = relu([mean|x]@Wcat + b1); p = h@W2l; s = h@W2r+b2 ----------
// 32 rows/block, 256 threads (4 waves); wave w owns cols w*64..w*64+63.
__global__ __launch_bounds__(256) void gemm1ps(
    const unsigned* __restrict__ mb, const unsigned* __restrict__ xb,
    const unsigned short* __restrict__ Wfrag, const float* __restrict__ b1,
    const float* __restrict__ W2l, const float* __restrict__ W2r,
    const float* __restrict__ b2,
    float* __restrict__ h, float* __restrict__ p, float* __restrict__ s) {
    __shared__ unsigned A[32 * 128];   // 16 KB, 16B-chunk XOR swizzled (k0-127: mean|x)
    __shared__ float ppart[32][4];     // p0,p1,s0,s1 partials per row

    int r0 = blockIdx.x * 32;
    int tid = threadIdx.x;
    int w = tid >> 6;          // 0..3
    int lane = tid & 63;
    int quad = lane >> 4;
    int l15 = lane & 15;

    if (tid < 128) ((float*)ppart)[tid] = 0.0f;

    // ---- stage A tile: thread t -> row t>>3, chunks (t&7)+8j; chunk<16=mean, else x ----
    int sr = tid >> 3;
    int c0 = tid & 7;
#pragma unroll
    for (int j = 0; j < 4; j++) {
        int c = c0 + (j << 3);             // 0..31
        uint4 v;
        if (c < 16) v = *(const uint4*)(mb + (size_t)(r0 + sr) * 64 + (c << 2));
        else        v = *(const uint4*)(xb + (size_t)(r0 + sr) * 64 + ((c - 16) << 2));
        int cp = c ^ (sr & 7);
        *(uint4*)(A + sr * 128 + (cp << 2)) = v;
    }
    __syncthreads();

    // ---- MFMA: 8 K-chunks of 32, 2 row-tiles x 4 col-tiles ----
    f32x4 acc[8];
#pragma unroll
    for (int i = 0; i < 8; i++) acc[i] = (f32x4){0.0f, 0.0f, 0.0f, 0.0f};

    for (int ks = 0; ks < 8; ks++) {
        bf16x8 bfr[4];
#pragma unroll
        for (int nt = 0; nt < 4; nt++) {
            int ntg = (w << 2) + nt;
            uint4 raw = *(const uint4*)(Wfrag + ((((ntg << 3) + ks) << 6) + lane) * 8);
            bfr[nt] = __builtin_bit_cast(bf16x8, raw);
        }
#pragma unroll
        for (int mt = 0; mt < 2; mt++) {
            int row = (mt << 4) + l15;
            int c = (ks << 2) + quad;
            uint4 araw = *(const uint4*)(A + row * 128 + ((c ^ (row & 7)) << 2));
            bf16x8 afr = __builtin_bit_cast(bf16x8, araw);
#pragma unroll
            for (int nt = 0; nt < 4; nt++) {
                acc[(mt << 2) + nt] = __builtin_amdgcn_mfma_f32_16x16x32_bf16(
                    afr, bfr[nt], acc[(mt << 2) + nt], 0, 0, 0);
            }
        }
    }

    // ---- epilogue: relu + nontemporal h store + ps partials ----
    float w2[4][4];
#pragma unroll
    for (int nt = 0; nt < 4; nt++) {
        int col = (w << 6) + (nt << 4) + l15;
        float2 l2 = *(const float2*)(W2l + col * 2);
        float2 r2 = *(const float2*)(W2r + col * 2);
        w2[nt][0] = l2.x; w2[nt][1] = l2.y; w2[nt][2] = r2.x; w2[nt][3] = r2.y;
    }

#pragma unroll
    for (int mt = 0; mt < 2; mt++) {
        float red[4][4];
#pragma unroll
        for (int v = 0; v < 4; v++)
#pragma unroll
            for (int r = 0; r < 4; r++) red[v][r] = 0.0f;

#pragma unroll
        for (int nt = 0; nt < 4; nt++) {
            int col = (w << 6) + (nt << 4) + l15;
            float b = b1[col];
            f32x4 v = acc[(mt << 2) + nt];
#pragma unroll
            for (int r = 0; r < 4; r++) {
                float hv = v[r] + b;
                hv = hv > 0.0f ? hv : 0.0f;
                int row = r0 + (mt << 4) + (quad << 2) + r;
                if (row < N_NODES)
                    __builtin_nontemporal_store(hv, &h[(size_t)row * 256 + col]);
                red[0][r] += hv * w2[nt][0];
                red[1][r] += hv * w2[nt][1];
                red[2][r] += hv * w2[nt][2];
                red[3][r] += hv * w2[nt][3];
            }
        }
#pragma unroll
        for (int v = 0; v < 4; v++)
#pragma unroll
            for (int r = 0; r < 4; r++) {
                red[v][r] += __shfl_xor(red[v][r], 1);
                red[v][r] += __shfl_xor(red[v][r], 2);
                red[v][r] += __shfl_xor(red[v][r], 4);
                red[v][r] += __shfl_xor(red[v][r], 8);
            }
        if (l15 == 0) {
            int lrow = (mt << 4) + (quad << 2);
#pragma unroll
            for (int r = 0; r < 4; r++)
#pragma unroll
                for (int v = 0; v < 4; v++)
                    atomicAdd(&ppart[lrow + r][v], red[v][r]);
        }
    }
    __syncthreads();

    if (tid < 32) {
        int row = r0 + tid;
        if (row < N_NODES) {
            float2 pv = {ppart[tid][0], ppart[tid][1]};
            float2 sv = {ppart[tid][2] + b2[0], ppart[tid][3] + b2[1]};
            *(float2*)(p + (size_t)row * 2) = pv;
            *(float2*)(s + (size_t)row * 2) = sv;
        }
    }
}

// ---------- layer-2: wave-per-node grid-stride, gather-mean of p + sigmoid ----------
__global__ __launch_bounds__(256) void agg2(
    const float* __restrict__ p, const float* __restrict__ s,
    const unsigned short* __restrict__ esrc,
    const int* __restrict__ rowbeg, const int* __restrict__ cnt,
    float* __restrict__ out) {
    int wid = (blockIdx.x * 256 + threadIdx.x) >> 6;
    int lane = threadIdx.x & 63;
    for (int d = wid; d < N_NODES; d += AGG_B * 4) {
        int beg = rowbeg[d];
        int c = cnt[d];
        int end = beg + c;
        float a0 = 0.0f, a1 = 0.0f;
        for (int base = beg; base < end; base += 64) {
            int idx = base + lane;
            if (idx < end) {
                int ss = (int)esrc[idx];
                float2 v = *(const float2*)(p + (size_t)ss * 2);
                a0 += v.x; a1 += v.y;
            }
        }
#pragma unroll
        for (int off = 32; off > 0; off >>= 1) {
            a0 += __shfl_down(a0, off);
            a1 += __shfl_down(a1, off);
        }
        if (lane == 0) {
            float inv = 1.0f / fmaxf((float)c, 1.0f);
            float z0 = a0 * inv + s[(size_t)d * 2 + 0];
            float z1 = a1 * inv + s[(size_t)d * 2 + 1];
            float2 o = {1.0f / (1.0f + expf(-z0)), 1.0f / (1.0f + expf(-z1))};
            *(float2*)(out + (size_t)d * 2) = o;
        }
    }
}

extern "C" void kernel_launch(void* const* d_in, const int* in_sizes, int n_in,
                              void* d_out, int out_size, void* d_ws, size_t ws_size,
                              hipStream_t stream) {
    const float* x   = (const float*)d_in[0];
    const int*   ei  = (const int*)d_in[1];
    const float* W1l = (const float*)d_in[2];
    const float* W1r = (const float*)d_in[3];
    const float* b1  = (const float*)d_in[4];
    const float* W2l = (const float*)d_in[5];
    const float* W2r = (const float*)d_in[6];
    const float* b2  = (const float*)d_in[7];

    const int* src = ei;
    const int* dst = ei + N_EDGES;

    float* out = (float*)d_out;               // [50000, 2]
    float* emb = out + (size_t)N_NODES * 2;   // [50000, 256] == h

    // ---- workspace layout (~29 MB); arr (CSR-build scratch, 12.8 MB) aliases mb:
    //      arr dead after scatter_kernel, mb written by agg1 afterwards ----
    int* cnt    = (int*)d_ws;                             // 50000
    int* rowbeg = cnt + N_NODES;                          // 50000
    int* bsum   = rowbeg + N_NODES;                       // 256
    unsigned short* esrc = (unsigned short*)(bsum + 256); // 800064 (16B-mult pad)
    unsigned* xb = (unsigned*)(esrc + 800064);            // 50048 x 64 uints
    unsigned* mb = xb + (size_t)50048 * 64;               // 50048 x 64 uints
    unsigned* arr = mb;                                   // 64 x 50000 uints (alias)
    unsigned short* Wfrag = (unsigned short*)(mb + (size_t)50048 * 64);  // 65536
    float* p = (float*)(Wfrag + 65536);                   // 100000
    float* s = p + (size_t)N_NODES * 2;                   // 100000

    prep<<<PREP_CVT_B + PREP_WF_B, 256, 0, stream>>>(x, W1l, W1r, xb, Wfrag);

    hist_kernel<<<NSLICE, 256, 0, stream>>>(dst, arr);
    scan1<<<NB_SCAN, 256, 0, stream>>>(arr, cnt, bsum);
    scanB<<<NB_SCAN, 256, 0, stream>>>(cnt, bsum, rowbeg);
    offs_kernel<<<NB_SCAN, 256, 0, stream>>>(rowbeg, arr);
    scatter_kernel<<<NSLICE * NPART, 256, 0, stream>>>(src, dst, arr, esrc);

    agg1<<<AGG_B, 256, 0, stream>>>(xb, mb, esrc, rowbeg, cnt);

    gemm1ps<<<GEMM_BLOCKS, 256, 0, stream>>>(mb, xb, Wfrag, b1, W2l, W2r, b2,
                                             emb, p, s);

    agg2<<<AGG_B, 256, 0, stream>>>(p, s, esrc, rowbeg, cnt, out);
}

// Round 11
// 226.397 us; speedup vs baseline: 1.2451x; 1.0567x over previous
//
#include <hip/hip_runtime.h>
#include <math.h>

#define N_NODES 50000
#define N_EDGES 800000
#define D_FEAT 128
#define HIDDEN 256
#define NB_SCAN 196           // ceil(50000/256)
#define GEMM_BLOCKS 1563      // ceil(50000/32)

#define PREP_CVT_B 512
#define PREP_WF_B 64
#define AGG_B 2048            // 8192 waves

#define NSLICE 64             // edge slices for CSR build
#define SLICE_E 12500         // 800000 / 64
#define NPART 8               // node partitions for scatter
#define PART_N 6250           // 50000 / 8

typedef __bf16 bf16x8 __attribute__((ext_vector_type(8)));
typedef float f32x4 __attribute__((ext_vector_type(4)));

__device__ __forceinline__ unsigned f2b(float f) {
    unsigned u = __builtin_bit_cast(unsigned, f);
    return (u + 0x7fff + ((u >> 16) & 1)) >> 16;  // RNE, low 16 bits valid
}

// ---------- fused prep: cvt_x | build_wfrag ----------
// xb[node][64 uints]: packed bf16 pairs of x (256 B/row, compact)
__global__ __launch_bounds__(256) void prep(
    const float* __restrict__ x,
    const float* __restrict__ W1l, const float* __restrict__ W1r,
    unsigned* __restrict__ xb, unsigned short* __restrict__ Wfrag) {
    int b = blockIdx.x;
    int t = threadIdx.x;
    if (b < PREP_CVT_B) {
        for (int g = b * 256 + t; g < 800000; g += PREP_CVT_B * 256) {
            float4 v0 = *(const float4*)(x + (size_t)g * 8);
            float4 v1 = *(const float4*)(x + (size_t)g * 8 + 4);
            uint4 o;
            o.x = f2b(v0.x) | (f2b(v0.y) << 16);
            o.y = f2b(v0.z) | (f2b(v0.w) << 16);
            o.z = f2b(v1.x) | (f2b(v1.y) << 16);
            o.w = f2b(v1.z) | (f2b(v1.w) << 16);
            int d = g >> 4;
            int j = (g & 15) << 2;
            *(uint4*)(xb + (size_t)d * 64 + j) = o;
        }
    } else {
        for (int tt = (b - PREP_CVT_B) * 256 + t; tt < 65536; tt += PREP_WF_B * 256) {
            int j = tt & 7;
            int lane = (tt >> 3) & 63;
            int ks = (tt >> 9) & 7;
            int nt = tt >> 12;
            int k = ks * 32 + ((lane >> 4) << 3) + j;
            int n = (nt << 4) + (lane & 15);
            float v = (k < 128) ? W1l[k * 256 + n] : W1r[(k - 128) * 256 + n];
            Wfrag[tt] = (unsigned short)f2b(v);
        }
    }
}

// ---------- CSR step A: per-slice full histogram (LDS, u16-packed), 16 waves ----------
__global__ __launch_bounds__(1024) void hist_kernel(const int* __restrict__ dst,
                                                    unsigned* __restrict__ arr) {
    __shared__ unsigned hist[25000];   // 100 KB: 50000 u16 counters, 2 per word
    int i = blockIdx.x;
    int t = threadIdx.x;
    for (int k = t; k < 25000; k += 1024) hist[k] = 0;
    __syncthreads();
    int e0 = i * SLICE_E;
    for (int k = t; k < SLICE_E; k += 1024) {
        int d = dst[e0 + k];
        atomicAdd(&hist[d >> 1], (d & 1) ? 65536u : 1u);   // LDS atomic
    }
    __syncthreads();
    for (int d = t; d < N_NODES; d += 1024)
        arr[(size_t)i * N_NODES + d] = (hist[d >> 1] >> ((d & 1) << 4)) & 0xffffu;
}

// ---------- CSR step B: cnt[d] = sum over slices; per-block sums for scan ----------
__global__ void scan1(const unsigned* __restrict__ arr, int* __restrict__ cnt,
                      int* __restrict__ bsum) {
    __shared__ int tmp[256];
    int t = threadIdx.x;
    int i = blockIdx.x * 256 + t;
    int c = 0;
    if (i < N_NODES) {
        for (int k = 0; k < NSLICE; k++) c += (int)arr[(size_t)k * N_NODES + i];
        cnt[i] = c;
    }
    tmp[t] = c;
    __syncthreads();
    for (int off = 128; off > 0; off >>= 1) {
        if (t < off) tmp[t] += tmp[t + off];
        __syncthreads();
    }
    if (t == 0) bsum[blockIdx.x] = tmp[0];
}

// ---------- CSR step C: exclusive scan -> rowbeg, fused per-slice offset prefix ----------
__global__ void scanB(const int* __restrict__ cnt, const int* __restrict__ bsum,
                      int* __restrict__ rowbeg, unsigned* __restrict__ arr) {
    __shared__ int bs[256];
    __shared__ int tmp[256];
    int t = threadIdx.x;
    int b = blockIdx.x;
    bs[t] = (t < NB_SCAN) ? bsum[t] : 0;
    __syncthreads();
    for (int off = 1; off < 256; off <<= 1) {
        int y = (t >= off) ? bs[t - off] : 0;
        __syncthreads();
        bs[t] += y;
        __syncthreads();
    }
    int boff = (b == 0) ? 0 : bs[b - 1];
    int i = b * 256 + t;
    int v = (i < N_NODES) ? cnt[i] : 0;
    tmp[t] = v;
    __syncthreads();
    for (int off = 1; off < 256; off <<= 1) {
        int y = (t >= off) ? tmp[t - off] : 0;
        __syncthreads();
        tmp[t] += y;
        __syncthreads();
    }
    if (i < N_NODES) {
        unsigned running = (unsigned)(tmp[t] - v + boff);
        rowbeg[i] = (int)running;
        // fused offs: arr[k][i] <- global base for (slice k, node i)
#pragma unroll 4
        for (int k = 0; k < NSLICE; k++) {
            unsigned old = arr[(size_t)k * N_NODES + i];
            arr[(size_t)k * N_NODES + i] = running;
            running += old;
        }
    }
}

// ---------- CSR step D: deterministic scatter, LDS cursors only ----------
__global__ __launch_bounds__(256) void scatter_kernel(
    const int* __restrict__ src, const int* __restrict__ dst,
    const unsigned* __restrict__ arr, unsigned short* __restrict__ esrc) {
    __shared__ unsigned off[PART_N];   // 25 KB
    int g = blockIdx.x & 7;
    int i = blockIdx.x >> 3;
    int t = threadIdx.x;
    int lo = g * PART_N;
    for (int k = t; k < PART_N; k += 256)
        off[k] = arr[(size_t)i * N_NODES + lo + k];
    __syncthreads();
    int e0 = i * SLICE_E;
    for (int k = t; k < SLICE_E; k += 256) {
        int e = e0 + k;
        int d = dst[e];
        unsigned dl = (unsigned)(d - lo);
        if (dl < (unsigned)PART_N) {
            unsigned pos = atomicAdd(&off[dl], 1u);   // LDS atomic
            esrc[pos] = (unsigned short)src[e];
        }
    }
}

// ---------- agg1: wave-per-node, uint4 gather (4 edges/iter, 16 lanes/row) ----------
// lane = 16*g + i: g = edge-group (0..3), i = feature-chunk (features 8i..8i+7)
__global__ __launch_bounds__(256) void agg1(
    const unsigned* __restrict__ xb, unsigned* __restrict__ mb,
    const unsigned short* __restrict__ esrc,
    const int* __restrict__ rowbeg, const int* __restrict__ cnt) {
    int wid = (blockIdx.x * 256 + threadIdx.x) >> 6;   // 8192 waves
    int lane = threadIdx.x & 63;
    int g = lane >> 4;
    int i = lane & 15;
    for (int d = wid; d < N_NODES; d += AGG_B * 4) {
        int beg = rowbeg[d];
        int c = cnt[d];
        int end = beg + c;
        float acc[8];
#pragma unroll
        for (int f = 0; f < 8; f++) acc[f] = 0.0f;

        for (int base = beg; base < end; base += 64) {
            int m = end - base; if (m > 64) m = 64;
            int idx = base + lane;
            int e = (int)esrc[idx < end ? idx : end - 1];  // coalesced, clamped
            for (int j0 = 0; j0 < m; j0 += 4) {
                int ss = __shfl(e, j0 + g);                // per-lane src (bpermute)
                float sc = (j0 + g < m) ? 1.0f : 0.0f;
                uint4 u = *(const uint4*)(xb + (size_t)ss * 64 + (i << 2));
                acc[0] += sc * __builtin_bit_cast(float, u.x << 16);
                acc[1] += sc * __builtin_bit_cast(float, u.x & 0xffff0000u);
                acc[2] += sc * __builtin_bit_cast(float, u.y << 16);
                acc[3] += sc * __builtin_bit_cast(float, u.y & 0xffff0000u);
                acc[4] += sc * __builtin_bit_cast(float, u.z << 16);
                acc[5] += sc * __builtin_bit_cast(float, u.z & 0xffff0000u);
                acc[6] += sc * __builtin_bit_cast(float, u.w << 16);
                acc[7] += sc * __builtin_bit_cast(float, u.w & 0xffff0000u);
            }
        }
        // combine the 4 edge-groups: lanes {i, i+16, i+32, i+48}
#pragma unroll
        for (int f = 0; f < 8; f++) {
            acc[f] += __shfl_xor(acc[f], 16);
            acc[f] += __shfl_xor(acc[f], 32);
        }
        if (lane < 16) {
            float inv = 1.0f / fmaxf((float)c, 1.0f);
            uint4 o;
            o.x = f2b(acc[0] * inv) | (f2b(acc[1] * inv) << 16);
            o.y = f2b(acc[2] * inv) | (f2b(acc[3] * inv) << 16);
            o.z = f2b(acc[4] * inv) | (f2b(acc[5] * inv) << 16);
            o.w = f2b(acc[6] * inv) | (f2b(acc[7] * inv) << 16);
            *(uint4*)(mb + (size_t)d * 64 + (i << 2)) = o;
        }
    }
}

// ---------- gemm1 + fused ps: h = relu([mean|x]@Wcat + b1); p = h@W2l; s = h@W2r+b2 ----------
// 32 rows/block, 256 threads (4 waves); wave w owns cols w*64..w*64+63.
__global__ __launch_bounds__(256) void gemm1ps(
    const unsigned* __restrict__ mb, const unsigned* __restrict__ xb,
    const unsigned short* __restrict__ Wfrag, const float* __restrict__ b1,
    const float* __restrict__ W2l, const float* __restrict__ W2r,
    const float* __restrict__ b2,
    float* __restrict__ h, float* __restrict__ p, float* __restrict__ s) {
    __shared__ unsigned A[32 * 128];   // 16 KB, 16B-chunk XOR swizzled (k0-127: mean|x)
    __shared__ float ppart[32][4];     // p0,p1,s0,s1 partials per row

    int r0 = blockIdx.x * 32;
    int tid = threadIdx.x;
    int w = tid >> 6;          // 0..3
    int lane = tid & 63;
    int quad = lane >> 4;
    int l15 = lane & 15;

    if (tid < 128) ((float*)ppart)[tid] = 0.0f;

    int sr = tid >> 3;
    int c0 = tid & 7;
#pragma unroll
    for (int j = 0; j < 4; j++) {
        int c = c0 + (j << 3);             // 0..31
        uint4 v;
        if (c < 16) v = *(const uint4*)(mb + (size_t)(r0 + sr) * 64 + (c << 2));
        else        v = *(const uint4*)(xb + (size_t)(r0 + sr) * 64 + ((c - 16) << 2));
        int cp = c ^ (sr & 7);
        *(uint4*)(A + sr * 128 + (cp << 2)) = v;
    }
    __syncthreads();

    f32x4 acc[8];
#pragma unroll
    for (int i = 0; i < 8; i++) acc[i] = (f32x4){0.0f, 0.0f, 0.0f, 0.0f};

    for (int ks = 0; ks < 8; ks++) {
        bf16x8 bfr[4];
#pragma unroll
        for (int nt = 0; nt < 4; nt++) {
            int ntg = (w << 2) + nt;
            uint4 raw = *(const uint4*)(Wfrag + ((((ntg << 3) + ks) << 6) + lane) * 8);
            bfr[nt] = __builtin_bit_cast(bf16x8, raw);
        }
#pragma unroll
        for (int mt = 0; mt < 2; mt++) {
            int row = (mt << 4) + l15;
            int c = (ks << 2) + quad;
            uint4 araw = *(const uint4*)(A + row * 128 + ((c ^ (row & 7)) << 2));
            bf16x8 afr = __builtin_bit_cast(bf16x8, araw);
#pragma unroll
            for (int nt = 0; nt < 4; nt++) {
                acc[(mt << 2) + nt] = __builtin_amdgcn_mfma_f32_16x16x32_bf16(
                    afr, bfr[nt], acc[(mt << 2) + nt], 0, 0, 0);
            }
        }
    }

    float w2[4][4];
#pragma unroll
    for (int nt = 0; nt < 4; nt++) {
        int col = (w << 6) + (nt << 4) + l15;
        float2 l2 = *(const float2*)(W2l + col * 2);
        float2 r2 = *(const float2*)(W2r + col * 2);
        w2[nt][0] = l2.x; w2[nt][1] = l2.y; w2[nt][2] = r2.x; w2[nt][3] = r2.y;
    }

#pragma unroll
    for (int mt = 0; mt < 2; mt++) {
        float red[4][4];
#pragma unroll
        for (int v = 0; v < 4; v++)
#pragma unroll
            for (int r = 0; r < 4; r++) red[v][r] = 0.0f;

#pragma unroll
        for (int nt = 0; nt < 4; nt++) {
            int col = (w << 6) + (nt << 4) + l15;
            float b = b1[col];
            f32x4 v = acc[(mt << 2) + nt];
#pragma unroll
            for (int r = 0; r < 4; r++) {
                float hv = v[r] + b;
                hv = hv > 0.0f ? hv : 0.0f;
                int row = r0 + (mt << 4) + (quad << 2) + r;
                if (row < N_NODES)
                    __builtin_nontemporal_store(hv, &h[(size_t)row * 256 + col]);
                red[0][r] += hv * w2[nt][0];
                red[1][r] += hv * w2[nt][1];
                red[2][r] += hv * w2[nt][2];
                red[3][r] += hv * w2[nt][3];
            }
        }
#pragma unroll
        for (int v = 0; v < 4; v++)
#pragma unroll
            for (int r = 0; r < 4; r++) {
                red[v][r] += __shfl_xor(red[v][r], 1);
                red[v][r] += __shfl_xor(red[v][r], 2);
                red[v][r] += __shfl_xor(red[v][r], 4);
                red[v][r] += __shfl_xor(red[v][r], 8);
            }
        if (l15 == 0) {
            int lrow = (mt << 4) + (quad << 2);
#pragma unroll
            for (int r = 0; r < 4; r++)
#pragma unroll
                for (int v = 0; v < 4; v++)
                    atomicAdd(&ppart[lrow + r][v], red[v][r]);
        }
    }
    __syncthreads();

    if (tid < 32) {
        int row = r0 + tid;
        if (row < N_NODES) {
            float2 pv = {ppart[tid][0], ppart[tid][1]};
            float2 sv = {ppart[tid][2] + b2[0], ppart[tid][3] + b2[1]};
            *(float2*)(p + (size_t)row * 2) = pv;
            *(float2*)(s + (size_t)row * 2) = sv;
        }
    }
}

// ---------- layer-2: wave-per-node grid-stride, gather-mean of p + sigmoid ----------
__global__ __launch_bounds__(256) void agg2(
    const float* __restrict__ p, const float* __restrict__ s,
    const unsigned short* __restrict__ esrc,
    const int* __restrict__ rowbeg, const int* __restrict__ cnt,
    float* __restrict__ out) {
    int wid = (blockIdx.x * 256 + threadIdx.x) >> 6;
    int lane = threadIdx.x & 63;
    for (int d = wid; d < N_NODES; d += AGG_B * 4) {
        int beg = rowbeg[d];
        int c = cnt[d];
        int end = beg + c;
        float a0 = 0.0f, a1 = 0.0f;
        for (int base = beg; base < end; base += 64) {
            int idx = base + lane;
            if (idx < end) {
                int ss = (int)esrc[idx];
                float2 v = *(const float2*)(p + (size_t)ss * 2);
                a0 += v.x; a1 += v.y;
            }
        }
#pragma unroll
        for (int off = 32; off > 0; off >>= 1) {
            a0 += __shfl_down(a0, off);
            a1 += __shfl_down(a1, off);
        }
        if (lane == 0) {
            float inv = 1.0f / fmaxf((float)c, 1.0f);
            float z0 = a0 * inv + s[(size_t)d * 2 + 0];
            float z1 = a1 * inv + s[(size_t)d * 2 + 1];
            float2 o = {1.0f / (1.0f + expf(-z0)), 1.0f / (1.0f + expf(-z1))};
            *(float2*)(out + (size_t)d * 2) = o;
        }
    }
}

extern "C" void kernel_launch(void* const* d_in, const int* in_sizes, int n_in,
                              void* d_out, int out_size, void* d_ws, size_t ws_size,
                              hipStream_t stream) {
    const float* x   = (const float*)d_in[0];
    const int*   ei  = (const int*)d_in[1];
    const float* W1l = (const float*)d_in[2];
    const float* W1r = (const float*)d_in[3];
    const float* b1  = (const float*)d_in[4];
    const float* W2l = (const float*)d_in[5];
    const float* W2r = (const float*)d_in[6];
    const float* b2  = (const float*)d_in[7];

    const int* src = ei;
    const int* dst = ei + N_EDGES;

    float* out = (float*)d_out;               // [50000, 2]
    float* emb = out + (size_t)N_NODES * 2;   // [50000, 256] == h

    // ---- workspace layout (~29 MB); arr (12.8 MB) aliases mb (dead after scatter) ----
    int* cnt    = (int*)d_ws;                             // 50000
    int* rowbeg = cnt + N_NODES;                          // 50000
    int* bsum   = rowbeg + N_NODES;                       // 256
    unsigned short* esrc = (unsigned short*)(bsum + 256); // 800064 (16B-mult pad)
    unsigned* xb = (unsigned*)(esrc + 800064);            // 50048 x 64 uints
    unsigned* mb = xb + (size_t)50048 * 64;               // 50048 x 64 uints
    unsigned* arr = mb;                                   // 64 x 50000 uints (alias)
    unsigned short* Wfrag = (unsigned short*)(mb + (size_t)50048 * 64);  // 65536
    float* p = (float*)(Wfrag + 65536);                   // 100000
    float* s = p + (size_t)N_NODES * 2;                   // 100000

    prep<<<PREP_CVT_B + PREP_WF_B, 256, 0, stream>>>(x, W1l, W1r, xb, Wfrag);

    hist_kernel<<<NSLICE, 1024, 0, stream>>>(dst, arr);
    scan1<<<NB_SCAN, 256, 0, stream>>>(arr, cnt, bsum);
    scanB<<<NB_SCAN, 256, 0, stream>>>(cnt, bsum, rowbeg, arr);
    scatter_kernel<<<NSLICE * NPART, 256, 0, stream>>>(src, dst, arr, esrc);

    agg1<<<AGG_B, 256, 0, stream>>>(xb, mb, esrc, rowbeg, cnt);

    gemm1ps<<<GEMM_BLOCKS, 256, 0, stream>>>(mb, xb, Wfrag, b1, W2l, W2r, b2,
                                             emb, p, s);

    agg2<<<AGG_B, 256, 0, stream>>>(p, s, esrc, rowbeg, cnt, out);
}